// Round 1
// baseline (583.318 us; speedup 1.0000x reference)
//
#include <hip/hip_runtime.h>
#include <math.h>

// Problem constants
constexpr int N_TOKENS = 8192;
constexpr int D_MODEL  = 4096;
constexpr int N_EXP    = 256;

// GEMM tiling: 32 tokens x 256 experts per block, BK=16, double-buffered LDS.
constexpr int BM = 32;
constexpr int BK = 16;
constexpr int NC = D_MODEL / BK;   // 256 k-chunks

// logits[n,e] = sum_k H[n,k] * W[e,k]   (both K-major -> coalesced loads)
__global__ __launch_bounds__(256) void gate_gemm(
    const float* __restrict__ H, const float* __restrict__ W,
    float* __restrict__ logits)
{
    // As stride 36 keeps float4 rows 16B-aligned (36*4=144) and 2-way-max bank aliasing.
    // Bs stride 257 -> inner-loop read bank = (k + tx) % 32, conflict-free.
    __shared__ float As[2][BK][BM + 4];
    __shared__ float Bs[2][BK][N_EXP + 1];

    const int t    = threadIdx.x;
    const int tx   = t & 31;      // expert lane: experts tx + 32*j, j=0..7
    const int ty   = t >> 5;      // token group: tokens ty*4 .. ty*4+3
    const int tok0 = blockIdx.x * BM;

    // A staging: threads t<128 each load one float4: tokA = t>>2, kqA = t&3
    const int tokA = t >> 2;
    const int kqA  = t & 3;

    float4 pa;        // valid for t < 128
    float4 pb[4];     // B chunk: 256 experts x 16 k = 1024 float4 / 256 thr = 4 each

    float acc[4][8];
    #pragma unroll
    for (int i = 0; i < 4; ++i)
        #pragma unroll
        for (int j = 0; j < 8; ++j) acc[i][j] = 0.0f;

    auto issue_loads = [&](int kc) {
        if (t < 128)
            pa = *(const float4*)(H + (size_t)(tok0 + tokA) * D_MODEL + kc + kqA * 4);
        #pragma unroll
        for (int j = 0; j < 4; ++j) {
            const int flat = t + 256 * j;      // [0,1024)
            const int e    = flat >> 2;        // 0..255
            const int kq   = flat & 3;         // 0..3
            pb[j] = *(const float4*)(W + (size_t)e * D_MODEL + kc + kq * 4);
        }
    };

    auto write_lds = [&](int buf) {
        if (t < 128) {
            As[buf][kqA * 4 + 0][tokA] = pa.x;
            As[buf][kqA * 4 + 1][tokA] = pa.y;
            As[buf][kqA * 4 + 2][tokA] = pa.z;
            As[buf][kqA * 4 + 3][tokA] = pa.w;
        }
        #pragma unroll
        for (int j = 0; j < 4; ++j) {
            const int flat = t + 256 * j;
            const int e    = flat >> 2;
            const int kq   = flat & 3;
            Bs[buf][kq * 4 + 0][e] = pb[j].x;
            Bs[buf][kq * 4 + 1][e] = pb[j].y;
            Bs[buf][kq * 4 + 2][e] = pb[j].z;
            Bs[buf][kq * 4 + 3][e] = pb[j].w;
        }
    };

    issue_loads(0);
    write_lds(0);
    __syncthreads();

    for (int c = 0; c < NC; ++c) {
        const int buf = c & 1;
        if (c + 1 < NC) issue_loads((c + 1) * BK);

        #pragma unroll
        for (int k = 0; k < BK; ++k) {
            const float4 av = *(const float4*)&As[buf][k][ty * 4];
            float a0 = av.x, a1 = av.y, a2 = av.z, a3 = av.w;
            float b[8];
            #pragma unroll
            for (int j = 0; j < 8; ++j) b[j] = Bs[buf][k][tx + 32 * j];
            #pragma unroll
            for (int j = 0; j < 8; ++j) {
                acc[0][j] = fmaf(a0, b[j], acc[0][j]);
                acc[1][j] = fmaf(a1, b[j], acc[1][j]);
                acc[2][j] = fmaf(a2, b[j], acc[2][j]);
                acc[3][j] = fmaf(a3, b[j], acc[3][j]);
            }
        }

        if (c + 1 < NC) write_lds(buf ^ 1);
        __syncthreads();
    }

    // Epilogue: experts tx + 32*j -> consecutive lanes write consecutive dwords.
    #pragma unroll
    for (int i = 0; i < 4; ++i) {
        const size_t row = (size_t)(tok0 + ty * 4 + i) * N_EXP;
        #pragma unroll
        for (int j = 0; j < 8; ++j)
            logits[row + tx + 32 * j] = acc[i][j];
    }
}

// One thread per (token, group): scan 64 scores keeping top-2 (strict '>' matches
// jax.lax.top_k lower-index tie-break), combine 4 groups per token via LDS.
__global__ __launch_bounds__(64) void topk_kernel(
    const float* __restrict__ logits,
    float* __restrict__ out_idx, float* __restrict__ out_w)
{
    const int t     = blockIdx.x * 64 + threadIdx.x;  // (token,group) id
    const int token = t >> 2;
    const int g     = t & 3;
    const float* row = logits + (size_t)token * N_EXP + g * 64;

    float v1 = -1.0f, v2 = -1.0f;   // sigmoid in (0,1) so -1 is a safe sentinel
    int   i1 = 0,     i2 = 0;
    for (int i = 0; i < 64; ++i) {
        const float x = row[i];
        const float s = 1.0f / (1.0f + expf(-x));
        if (s > v1)      { v2 = v1; i2 = i1; v1 = s; i1 = i; }
        else if (s > v2) { v2 = s;  i2 = i; }
    }

    __shared__ float sv[16][8];
    __shared__ int   si[16][8];
    const int tl = threadIdx.x >> 2;
    sv[tl][g * 2 + 0] = v1;
    sv[tl][g * 2 + 1] = v2;
    si[tl][g * 2 + 0] = g * 64 + i1;
    si[tl][g * 2 + 1] = g * 64 + i2;
    __syncthreads();

    if (threadIdx.x < 16) {
        const int ltok = threadIdx.x;
        const size_t gtok = (size_t)blockIdx.x * 16 + ltok;
        float sum = 0.0f;
        #pragma unroll
        for (int j = 0; j < 8; ++j) sum += sv[ltok][j];
        const float scale = 2.5f / (sum + 1e-10f);
        #pragma unroll
        for (int j = 0; j < 8; ++j) {
            out_idx[gtok * 8 + j] = (float)si[ltok][j];
            out_w  [gtok * 8 + j] = sv[ltok][j] * scale;
        }
    }
}

extern "C" void kernel_launch(void* const* d_in, const int* in_sizes, int n_in,
                              void* d_out, int out_size, void* d_ws, size_t ws_size,
                              hipStream_t stream) {
    const float* H = (const float*)d_in[0];   // hidden_states [8192, 4096]
    const float* W = (const float*)d_in[1];   // gate_w        [256, 4096]

    float* out      = (float*)d_out;
    float* out_idx  = out;                                   // 8192*8
    float* out_w    = out + (size_t)N_TOKENS * 8;            // 8192*8
    float* logits   = out + (size_t)N_TOKENS * 16;           // 8192*256

    gate_gemm<<<dim3(N_TOKENS / BM), dim3(256), 0, stream>>>(H, W, logits);
    topk_kernel<<<dim3(N_TOKENS * 4 / 64), dim3(64), 0, stream>>>(logits, out_idx, out_w);
}